// Round 1
// baseline (221.251 us; speedup 1.0000x reference)
//
#include <hip/hip_runtime.h>

#define BATCH 16
#define HI 384
#define WI 384
#define CH 32
#define OUT_H 384
#define OUT_W 384
#define HW (HI * WI)
#define NBLK 32  // partial-sum blocks per batch image

// ---------------------------------------------------------------------------
// Kernel 1: per-(batch, channel) partial sums over a slice of HW pixels.
// Each block owns (b, sub) and writes its own 32-float partial vector to ws —
// no zero-init, no atomics, fully deterministic.
// Layout: thread t -> c4 = t&7 (float4 channel group), poff = t>>3 (pixel
// offset 0..31). A wave reads 8 consecutive pixels * 128B = 1KB contiguous.
// ---------------------------------------------------------------------------
__global__ __launch_bounds__(256) void k_partial_sums(
    const float* __restrict__ X, float* __restrict__ partials) {
  const int blk = blockIdx.x;  // [0, BATCH*NBLK)
  const int b = blk / NBLK;
  const int sub = blk % NBLK;
  const int t = threadIdx.x;
  const int c4 = t & 7;
  const int poff = t >> 3;  // 0..31
  const int pixels_per_blk = HW / NBLK;  // 4608
  const int p0 = sub * pixels_per_blk;

  const float4* base = (const float4*)(X + (size_t)b * HW * CH);
  float4 acc = make_float4(0.f, 0.f, 0.f, 0.f);
  for (int p = p0 + poff; p < p0 + pixels_per_blk; p += 32) {
    float4 v = base[(size_t)p * 8 + c4];
    acc.x += v.x; acc.y += v.y; acc.z += v.z; acc.w += v.w;
  }

  __shared__ float4 sh[256];
  sh[t] = acc;
  __syncthreads();
  if (t < 8) {
    float4 s = make_float4(0.f, 0.f, 0.f, 0.f);
    for (int i = 0; i < 32; ++i) {
      float4 v = sh[i * 8 + t];
      s.x += v.x; s.y += v.y; s.z += v.z; s.w += v.w;
    }
    ((float4*)(partials + (size_t)blk * CH))[t] = s;
  }
}

// ---------------------------------------------------------------------------
// Kernel 2: reduce partials -> feat [B,32] (in LDS), then theta = feat@W + b.
// One block of 512 threads. theta written to ws after the partials region.
// ---------------------------------------------------------------------------
__global__ __launch_bounds__(512) void k_theta(
    const float* __restrict__ partials, const float* __restrict__ Wl,
    const float* __restrict__ bl, float* __restrict__ theta) {
  __shared__ float feat[BATCH * CH];  // 512
  const int t = threadIdx.x;
  {
    const int b = t >> 5, c = t & 31;
    float s = 0.f;
    for (int i = 0; i < NBLK; ++i)
      s += partials[((size_t)b * NBLK + i) * CH + c];
    feat[t] = s * (1.0f / (float)HW);
  }
  __syncthreads();
  if (t < BATCH * 6) {
    const int b = t / 6, j = t % 6;
    float s = bl[j];
    for (int c = 0; c < CH; ++c) s += feat[b * CH + c] * Wl[c * 6 + j];
    theta[t] = s;
  }
}

// ---------------------------------------------------------------------------
// Kernel 3: affine grid + bilinear sample. 8 threads per output pixel
// (float4 each over C=32). Each 8-lane cluster gathers 4 contiguous 128B
// segments (the 4 bilinear corners) and writes 128B coalesced.
// Math matches the reference exactly: floor -> weights from unclipped fracs,
// indices clipped to [0, 383].
// ---------------------------------------------------------------------------
__global__ __launch_bounds__(256) void k_sample(
    const float* __restrict__ X, const float* __restrict__ theta,
    float* __restrict__ out) {
  const int gid = blockIdx.x * 256 + threadIdx.x;  // < 18.9M, fits int32
  const int c4 = gid & 7;
  const int n = gid >> 3;  // output pixel index
  const int b = n / (OUT_H * OUT_W);
  const int p = n % (OUT_H * OUT_W);
  const int oy = p / OUT_W;
  const int ox = p % OUT_W;

  const float* th = theta + b * 6;
  const float gx = fmaf((float)ox, 2.0f / (float)(OUT_W - 1), -1.0f);
  const float gy = fmaf((float)oy, 2.0f / (float)(OUT_H - 1), -1.0f);
  const float sx = th[0] * gx + th[1] * gy + th[2];
  const float sy = th[3] * gx + th[4] * gy + th[5];
  const float x = (sx + 1.0f) * 0.5f * (float)(WI - 1);
  const float y = (sy + 1.0f) * 0.5f * (float)(HI - 1);

  const float x0f = floorf(x), y0f = floorf(y);
  const float wx1 = x - x0f, wx0 = 1.0f - wx1;
  const float wy1 = y - y0f, wy0 = 1.0f - wy1;
  const int x0 = min(max((int)x0f, 0), WI - 1);
  const int x1 = min(max((int)x0f + 1, 0), WI - 1);
  const int y0 = min(max((int)y0f, 0), HI - 1);
  const int y1 = min(max((int)y0f + 1, 0), HI - 1);

  const float4* img = (const float4*)(X + (size_t)b * HW * CH);
  const float4 g00 = img[((size_t)y0 * WI + x0) * 8 + c4];
  const float4 g01 = img[((size_t)y0 * WI + x1) * 8 + c4];
  const float4 g10 = img[((size_t)y1 * WI + x0) * 8 + c4];
  const float4 g11 = img[((size_t)y1 * WI + x1) * 8 + c4];

  const float w00 = wy0 * wx0, w01 = wy0 * wx1;
  const float w10 = wy1 * wx0, w11 = wy1 * wx1;

  float4 r;
  r.x = g00.x * w00 + g01.x * w01 + g10.x * w10 + g11.x * w11;
  r.y = g00.y * w00 + g01.y * w01 + g10.y * w10 + g11.y * w11;
  r.z = g00.z * w00 + g01.z * w01 + g10.z * w10 + g11.z * w11;
  r.w = g00.w * w00 + g01.w * w01 + g10.w * w10 + g11.w * w11;
  ((float4*)out)[gid] = r;
}

extern "C" void kernel_launch(void* const* d_in, const int* in_sizes, int n_in,
                              void* d_out, int out_size, void* d_ws,
                              size_t ws_size, hipStream_t stream) {
  const float* X = (const float*)d_in[0];
  const float* Wl = (const float*)d_in[1];
  const float* bl = (const float*)d_in[2];
  float* out = (float*)d_out;

  float* partials = (float*)d_ws;                       // BATCH*NBLK*CH floats
  float* theta = partials + (size_t)BATCH * NBLK * CH;  // BATCH*6 floats

  k_partial_sums<<<BATCH * NBLK, 256, 0, stream>>>(X, partials);
  k_theta<<<1, 512, 0, stream>>>(partials, Wl, bl, theta);

  const int total = BATCH * OUT_H * OUT_W * 8;  // threads (8 per pixel)
  k_sample<<<total / 256, 256, 0, stream>>>(X, theta, out);
}

// Round 3
// 175.823 us; speedup vs baseline: 1.2584x; 1.2584x over previous
//
#include <hip/hip_runtime.h>

#define BATCH 16
#define HI 384
#define WI 384
#define CH 32
#define OUT_H 384
#define OUT_W 384
#define HW (HI * WI)
#define NBLK 64  // partial-sum blocks per batch image

typedef float f32x4 __attribute__((ext_vector_type(4)));

// ---------------------------------------------------------------------------
// Kernel 1: per-(batch, channel) partial sums over a slice of HW pixels.
// Each block owns (b, sub) and writes its own 32-float partial vector to ws —
// no zero-init, no atomics, fully deterministic.
// Thread t -> c4 = t&7 (float4 channel group), poff = t>>3 (pixel offset).
// A wave reads 8 consecutive pixels * 128B = 1KB contiguous per iteration.
// ---------------------------------------------------------------------------
__global__ __launch_bounds__(256) void k_partial_sums(
    const float* __restrict__ X, float* __restrict__ partials) {
  const int blk = blockIdx.x;  // [0, BATCH*NBLK)
  const int b = blk / NBLK;
  const int sub = blk % NBLK;
  const int t = threadIdx.x;
  const int c4 = t & 7;
  const int poff = t >> 3;               // 0..31
  const int pixels_per_blk = HW / NBLK;  // 2304
  const int p0 = sub * pixels_per_blk;

  const f32x4* base = (const f32x4*)(X + (size_t)b * HW * CH);
  f32x4 acc = {0.f, 0.f, 0.f, 0.f};
#pragma unroll 4
  for (int p = p0 + poff; p < p0 + pixels_per_blk; p += 32) {
    acc += base[(size_t)p * 8 + c4];
  }

  __shared__ f32x4 sh[256];
  sh[t] = acc;
  __syncthreads();
  if (t < 8) {
    f32x4 s = {0.f, 0.f, 0.f, 0.f};
    for (int i = 0; i < 32; ++i) s += sh[i * 8 + t];
    ((f32x4*)(partials + (size_t)blk * CH))[t] = s;
  }
}

// ---------------------------------------------------------------------------
// Kernel 2: reduce partials -> feat [B,32] (in LDS), then theta = feat@W + b.
// One block of 512 threads.
// ---------------------------------------------------------------------------
__global__ __launch_bounds__(512) void k_theta(
    const float* __restrict__ partials, const float* __restrict__ Wl,
    const float* __restrict__ bl, float* __restrict__ theta) {
  __shared__ float feat[BATCH * CH];  // 512
  const int t = threadIdx.x;
  {
    const int b = t >> 5, c = t & 31;
    float s = 0.f;
    for (int i = 0; i < NBLK; ++i)
      s += partials[((size_t)b * NBLK + i) * CH + c];
    feat[t] = s * (1.0f / (float)HW);
  }
  __syncthreads();
  if (t < BATCH * 6) {
    const int b = t / 6, j = t % 6;
    float s = bl[j];
    for (int c = 0; c < CH; ++c) s += feat[b * CH + c] * Wl[c * 6 + j];
    theta[t] = s;
  }
}

// ---------------------------------------------------------------------------
// Kernel 3: affine grid + bilinear sample. 8 threads per output pixel
// (f32x4 each over C=32). Each 8-lane cluster gathers 4 contiguous 128B
// segments (the 4 bilinear corners) and writes 128B coalesced (nontemporal,
// keeps L2 for the gather).
// XCD swizzle: remap dispatch id so each XCD owns a CONTIGUOUS slab of
// output pixels -> adjacent output rows (which share input rows y0/y1) hit
// the SAME per-XCD L2 instead of re-fetching on another chiplet.
// Math matches the reference exactly: floor -> weights from unclipped fracs,
// indices clipped to [0, 383].
// ---------------------------------------------------------------------------
__global__ __launch_bounds__(256) void k_sample(
    const float* __restrict__ X, const float* __restrict__ theta,
    float* __restrict__ out) {
  // bijective XCD swizzle (gridDim.x = 73728, divisible by 8)
  const int q = gridDim.x >> 3;
  const int bid = blockIdx.x;
  const int blk = (bid & 7) * q + (bid >> 3);

  const int gid = blk * 256 + threadIdx.x;  // < 18.9M, fits int32
  const int c4 = gid & 7;
  const int n = gid >> 3;  // output pixel index
  const int b = n / (OUT_H * OUT_W);
  const int p = n % (OUT_H * OUT_W);
  const int oy = p / OUT_W;
  const int ox = p % OUT_W;

  const float* th = theta + b * 6;
  const float gx = fmaf((float)ox, 2.0f / (float)(OUT_W - 1), -1.0f);
  const float gy = fmaf((float)oy, 2.0f / (float)(OUT_H - 1), -1.0f);
  const float sx = th[0] * gx + th[1] * gy + th[2];
  const float sy = th[3] * gx + th[4] * gy + th[5];
  const float x = (sx + 1.0f) * 0.5f * (float)(WI - 1);
  const float y = (sy + 1.0f) * 0.5f * (float)(HI - 1);

  const float x0f = floorf(x), y0f = floorf(y);
  const float wx1 = x - x0f, wx0 = 1.0f - wx1;
  const float wy1 = y - y0f, wy0 = 1.0f - wy1;
  const int x0 = min(max((int)x0f, 0), WI - 1);
  const int x1 = min(max((int)x0f + 1, 0), WI - 1);
  const int y0 = min(max((int)y0f, 0), HI - 1);
  const int y1 = min(max((int)y0f + 1, 0), HI - 1);

  const f32x4* img = (const f32x4*)(X + (size_t)b * HW * CH);
  const f32x4 g00 = img[((size_t)y0 * WI + x0) * 8 + c4];
  const f32x4 g01 = img[((size_t)y0 * WI + x1) * 8 + c4];
  const f32x4 g10 = img[((size_t)y1 * WI + x0) * 8 + c4];
  const f32x4 g11 = img[((size_t)y1 * WI + x1) * 8 + c4];

  const float w00 = wy0 * wx0, w01 = wy0 * wx1;
  const float w10 = wy1 * wx0, w11 = wy1 * wx1;

  f32x4 r = g00 * w00 + g01 * w01 + g10 * w10 + g11 * w11;
  __builtin_nontemporal_store(r, &((f32x4*)out)[gid]);
}

extern "C" void kernel_launch(void* const* d_in, const int* in_sizes, int n_in,
                              void* d_out, int out_size, void* d_ws,
                              size_t ws_size, hipStream_t stream) {
  const float* X = (const float*)d_in[0];
  const float* Wl = (const float*)d_in[1];
  const float* bl = (const float*)d_in[2];
  float* out = (float*)d_out;

  float* partials = (float*)d_ws;                       // BATCH*NBLK*CH floats
  float* theta = partials + (size_t)BATCH * NBLK * CH;  // BATCH*6 floats

  k_partial_sums<<<BATCH * NBLK, 256, 0, stream>>>(X, partials);
  k_theta<<<1, 512, 0, stream>>>(partials, Wl, bl, theta);

  const int total = BATCH * OUT_H * OUT_W * 8;  // threads (8 per pixel)
  k_sample<<<total / 256, 256, 0, stream>>>(X, theta, out);
}